// Round 7
// baseline (378.193 us; speedup 1.0000x reference)
//
#include <hip/hip_runtime.h>
#include <hip/hip_bf16.h>

#define BB 8
#define NN 2048
#define DD 128

typedef __attribute__((ext_vector_type(8))) __bf16 bf16x8;
typedef __attribute__((ext_vector_type(4))) float f32x4;
typedef __attribute__((ext_vector_type(4))) int   i32x4;

static __device__ __forceinline__ unsigned short f2bf(float f) {
    union { float f; unsigned u; } v; v.f = f;
    unsigned r = (v.u + 0x7FFFu + ((v.u >> 16) & 1u)) >> 16;
    return (unsigned short)r;
}
static __device__ __forceinline__ float bf2f(unsigned short b) {
    union { unsigned u; float f; } v; v.u = ((unsigned)b) << 16;
    return v.f;
}

// ---------------------------------------------------------------------------
// kernP v3: 2 rows/block, 8192 blocks. 128 threads/row load int4 CONTIGUOUSLY
// (lane u -> col 4u within a 512-col pass), nibble -> LDS, then 64 lanes/row
// pack 32-bit words via nibble-compress, clear diagonal, popc + wave-reduce
// -> scale. Block 8192 casts Wc to bf16.
// ---------------------------------------------------------------------------
__global__ __launch_bounds__(256) void kernP(
    const int* __restrict__ punct, const int* __restrict__ mask,
    const float* __restrict__ w_self, const float* __restrict__ w_punct,
    unsigned* __restrict__ pk, float* __restrict__ scale_g,
    unsigned short* __restrict__ wc)
{
    const int t = threadIdx.x;
    if (blockIdx.x == 8192) {
        for (int idx = t; idx < 128 * 256; idx += 256) {
            const int e = idx >> 8, k = idx & 255;
            const float v = (k < 128) ? w_self[e * 128 + k]
                                      : w_punct[e * 128 + (k - 128)];
            wc[idx] = f2bf(v);
        }
        return;
    }
    __shared__ unsigned char nib[2][512];

    const int rl = t >> 7;                    // row within block (0/1)
    const int u  = t & 127;
    const int row_g = blockIdx.x * 2 + rl;
    const int b = row_g >> 11;

    const int* prow = punct + (size_t)row_g * NN;
    const int* mrow = mask + (size_t)b * NN;

    #pragma unroll
    for (int p = 0; p < 4; ++p) {
        const int col = p * 512 + u * 4;      // consecutive u -> consecutive 16B
        i32x4 pv = *(const i32x4*)(prow + col);
        i32x4 mv = *(const i32x4*)(mrow + col);
        unsigned n = (unsigned)((pv.x & mv.x & 1) | ((pv.y & mv.y & 1) << 1)
                              | ((pv.z & mv.z & 1) << 2) | ((pv.w & mv.w & 1) << 3));
        nib[rl][p * 128 + u] = (unsigned char)n;
    }
    __syncthreads();

    if (t < 128) {
        const int r2 = t >> 6, w = t & 63;    // wave 0 -> row 0, wave 1 -> row 1
        const int rg2 = blockIdx.x * 2 + r2;
        const int i2 = rg2 & (NN - 1);
        const unsigned* np = (const unsigned*)&nib[r2][w * 8];
        unsigned a = np[0], c = np[1];
        a = (a | (a >> 4)) & 0x00FF00FFu;  a = (a | (a >> 8)) & 0x0000FFFFu;
        c = (c | (c >> 4)) & 0x00FF00FFu;  c = (c | (c >> 8)) & 0x0000FFFFu;
        unsigned pw = a | (c << 16);
        if ((i2 >> 5) == w) pw &= ~(1u << (i2 & 31));     // zero diagonal
        pk[(size_t)rg2 * 64 + w] = pw;

        int cnt = __popc(pw);
        #pragma unroll
        for (int o = 32; o > 0; o >>= 1) cnt += __shfl_xor(cnt, o, 64);
        if (w == 0) {
            const int mi = mask[(size_t)(rg2 >> 11) * NN + i2];
            scale_g[rg2] = mi ? 1.f / (float)(cnt < 1 ? 1 : cnt) : 0.f;
        }
    }
}

// ---------------------------------------------------------------------------
// kernD v2 (step-0 prologue): 16 rows/block, 1024 blocks. Single coalesced
// pass: thread t -> row t>>4, 8 contiguous cols at (t&15)*8. dw via 16-lane
// shuffle reduce. Writes ab[:, :128]=bf16(x), aw[:,0,:], xwT=(dw*x)^T.
// ---------------------------------------------------------------------------
__global__ __launch_bounds__(256) void kernD(
    const float* __restrict__ x,
    const float* __restrict__ w_nw, const float* __restrict__ b_nw,
    float* __restrict__ aw_out,
    unsigned short* __restrict__ ab, unsigned short* __restrict__ xwT)
{
    __shared__ float wnw_l[DD];
    __shared__ float red_l[16];
    __shared__ float dw_l[16];
    __shared__ unsigned short xl[16 * 136];

    const int t  = threadIdx.x;
    const int n0 = blockIdx.x * 16;
    const int b  = n0 >> 11;
    const int nb = n0 & (NN - 1);

    if (t < DD) wnw_l[t] = w_nw[t];
    __syncthreads();

    const int row = t >> 4, c0 = (t & 15) * 8;
    const float* xs = x + (size_t)(n0 + row) * DD + c0;
    f32x4 a0 = *(const f32x4*)xs;
    f32x4 a1 = *(const f32x4*)(xs + 4);
    const float* wv = &wnw_l[c0];
    float dp = a0.x*wv[0] + a0.y*wv[1] + a0.z*wv[2] + a0.w*wv[3]
             + a1.x*wv[4] + a1.y*wv[5] + a1.z*wv[6] + a1.w*wv[7];
    #pragma unroll
    for (int o = 8; o > 0; o >>= 1) dp += __shfl_xor(dp, o, 64);
    if ((t & 15) == 0) red_l[row] = dp;

    unsigned w0 = f2bf(a0.x) | ((unsigned)f2bf(a0.y) << 16);
    unsigned w1 = f2bf(a0.z) | ((unsigned)f2bf(a0.w) << 16);
    unsigned w2 = f2bf(a1.x) | ((unsigned)f2bf(a1.y) << 16);
    unsigned w3 = f2bf(a1.z) | ((unsigned)f2bf(a1.w) << 16);
    i32x4 pw = {(int)w0,(int)w1,(int)w2,(int)w3};
    *(i32x4*)(ab + (size_t)(n0 + row) * 256 + c0) = pw;
    *(i32x4*)&xl[row * 136 + c0] = pw;
    __syncthreads();

    if (t < 16) {
        float s = red_l[t] + b_nw[0];
        float dv = 1.f / (1.f + __expf(-s));
        dw_l[t] = dv;
        aw_out[(size_t)b * 2 * NN + nb + t] = dv;
    }
    __syncthreads();

    {   // xwT: thread t -> (d = t>>1, half = t&1), 8 rows each
        const int d = t >> 1, half = t & 1;
        unsigned o[4];
        #pragma unroll
        for (int k = 0; k < 4; ++k) {
            const int r0 = half * 8 + 2 * k;
            const float lo = bf2f(xl[r0 * 136 + d]) * dw_l[r0];
            const float hi = bf2f(xl[(r0 + 1) * 136 + d]) * dw_l[r0 + 1];
            o[k] = f2bf(lo) | ((unsigned)f2bf(hi) << 16);
        }
        i32x4 v = {(int)o[0],(int)o[1],(int)o[2],(int)o[3]};
        *(i32x4*)(xwT + (size_t)(b * DD + d) * NN + nb + half * 8) = v;
    }
}

// ---------------------------------------------------------------------------
// kernC2 v3: Z = bitP @ xwT. 32 rows/block, 512 blocks, 512 THREADS
// (8 waves). Wave (wm,wn): rows wm*16, d-slice wn*32. Zero barriers in the
// K-loop. Zs = scale*Z -> ab[:, 128:256] bf16.
// ---------------------------------------------------------------------------
__global__ __launch_bounds__(512) void kernC2(
    const unsigned* __restrict__ pk, const float* __restrict__ scale_g,
    const unsigned short* __restrict__ xwT,   // [B][D][N]
    unsigned short* __restrict__ ab)          // [B*N][256], cols 128..255
{
    __shared__ unsigned pPk[32 * 68];
    __shared__ float scale_l[32];

    const int t  = threadIdx.x;
    const int b  = blockIdx.x >> 6;
    const int i0 = (blockIdx.x & 63) * 32;
    const size_t rg0 = (size_t)b * NN + i0;

    {   // stage bits: 32 rows x 16 vec4 = 512 vec4, one per thread
        const int row = t >> 4, wq = (t & 15) * 4;
        i32x4 v = *(const i32x4*)(pk + (rg0 + row) * 64 + wq);
        *(i32x4*)&pPk[row * 68 + wq] = v;
    }
    if (t < 32) scale_l[t] = scale_g[rg0 + t];
    __syncthreads();

    const int wv = t >> 6, lane = t & 63;
    const int wm = wv >> 2, wn = wv & 3;
    const int quad = lane >> 4, l16 = lane & 15;
    const unsigned short* xwTb = xwT + (size_t)b * DD * NN;

    f32x4 acc[2] = {};
    #pragma unroll 4
    for (int kk = 0; kk < 64; ++kk) {
        bf16x8 bfr[2];
        #pragma unroll
        for (int nt = 0; nt < 2; ++nt) {
            const int d = wn*32 + nt*16 + l16;
            bfr[nt] = *(const bf16x8*)(xwTb + (size_t)d * NN + kk*32 + quad*8);
        }
        const unsigned w = pPk[(wm*16 + l16) * 68 + kk];
        const unsigned by = (w >> (quad * 8)) & 0xFFu;
        i32x4 ex;
        ex.x = ((by &   1u) ? 0x3F80 : 0) | ((by &   2u) ? 0x3F800000 : 0);
        ex.y = ((by &   4u) ? 0x3F80 : 0) | ((by &   8u) ? 0x3F800000 : 0);
        ex.z = ((by &  16u) ? 0x3F80 : 0) | ((by &  32u) ? 0x3F800000 : 0);
        ex.w = ((by &  64u) ? 0x3F80 : 0) | ((by & 128u) ? 0x3F800000 : 0);
        union { i32x4 i; bf16x8 h; } cv; cv.i = ex;
        #pragma unroll
        for (int nt = 0; nt < 2; ++nt)
            acc[nt] = __builtin_amdgcn_mfma_f32_16x16x32_bf16(cv.h, bfr[nt], acc[nt], 0, 0, 0);
    }

    #pragma unroll
    for (int nt = 0; nt < 2; ++nt) {
        const int d = wn*32 + nt*16 + l16;
        #pragma unroll
        for (int r = 0; r < 4; ++r) {
            const int row = wm*16 + quad*4 + r;
            ab[(rg0 + row) * 256 + 128 + d] = f2bf(scale_l[row] * acc[nt][r]);
        }
    }
}

// ---------------------------------------------------------------------------
// kernF v2: out = relu([xbf|Zs] @ Wc^T + b_self), 32 rows/block, 512 blocks.
// want_x: write x_out f32 (final step). want_next: write ab_next[:, :128],
// xwT_next for the next step. dw_next -> aw_next always.
// ---------------------------------------------------------------------------
__global__ __launch_bounds__(256) void kernF(
    const unsigned short* __restrict__ ab,    // [B*N][256]
    const unsigned short* __restrict__ wc,    // [128][256]
    const float* __restrict__ b_self,
    const float* __restrict__ w_nw, const float* __restrict__ b_nw,
    float* __restrict__ x_out, float* __restrict__ aw_next,
    unsigned short* __restrict__ ab_next, unsigned short* __restrict__ xwT_next,
    int want_x, int want_next)
{
    __shared__ unsigned short xl[32 * 136];
    __shared__ float red[32 * 68];
    __shared__ float dw_l[32];

    const int t  = threadIdx.x;
    const int b  = blockIdx.x >> 6;
    const int i0 = (blockIdx.x & 63) * 32;
    const size_t rg0 = (size_t)b * NN + i0;

    const int wn = t >> 6, lane = t & 63;
    const int quad = lane >> 4, l16 = lane & 15;

    f32x4 acc[2][2] = {};
    #pragma unroll
    for (int kq = 0; kq < 8; ++kq) {
        bf16x8 b2[2];
        #pragma unroll
        for (int nt = 0; nt < 2; ++nt) {
            const int e = wn*32 + nt*16 + l16;
            b2[nt] = *(const bf16x8*)(wc + (size_t)e * 256 + kq*32 + quad*8);
        }
        bf16x8 a2[2];
        #pragma unroll
        for (int mt = 0; mt < 2; ++mt)
            a2[mt] = *(const bf16x8*)(ab + (rg0 + mt*16 + l16) * 256 + kq*32 + quad*8);
        #pragma unroll
        for (int mt = 0; mt < 2; ++mt)
            #pragma unroll
            for (int nt = 0; nt < 2; ++nt)
                acc[mt][nt] = __builtin_amdgcn_mfma_f32_16x16x32_bf16(a2[mt], b2[nt], acc[mt][nt], 0, 0, 0);
    }

    float bias[2], wnv[2];
    #pragma unroll
    for (int nt = 0; nt < 2; ++nt) {
        const int e = wn*32 + nt*16 + l16;
        bias[nt] = b_self[e];
        wnv[nt]  = w_nw[e];
    }
    #pragma unroll
    for (int mt = 0; mt < 2; ++mt) {
        #pragma unroll
        for (int r = 0; r < 4; ++r) {
            const int row = mt*16 + quad*4 + r;
            float p = 0.f;
            #pragma unroll
            for (int nt = 0; nt < 2; ++nt) {
                const int e = wn*32 + nt*16 + l16;
                float v = fmaxf(acc[mt][nt][r] + bias[nt], 0.f);
                if (want_x) x_out[(rg0 + row) * DD + e] = v;
                xl[row * 136 + e] = f2bf(v);
                p += v * wnv[nt];
            }
            red[row * 68 + wn*16 + l16] = p;
        }
    }
    __syncthreads();
    if (t < 32) {
        float s = b_nw[0];
        #pragma unroll 8
        for (int c = 0; c < 64; ++c) s += red[t * 68 + c];
        float dv = 1.f / (1.f + __expf(-s));
        dw_l[t] = dv;
        aw_next[(size_t)b * 2 * NN + i0 + t] = dv;
    }
    __syncthreads();

    if (want_next) {
        {   // ab_next[:, :128] = bf16(x_new): 8 thr/row, 16 cols (2 x i32x4) each
            const int row = t >> 3, q = t & 7;
            i32x4 v0 = *(const i32x4*)&xl[row * 136 + q * 16];
            i32x4 v1 = *(const i32x4*)&xl[row * 136 + q * 16 + 8];
            i32x4* dst = (i32x4*)(ab_next + (rg0 + row) * 256 + q * 16);
            dst[0] = v0; dst[1] = v1;       // R6 bug: only dst[0] was written
        }
        {   // xwT_next = (dw*x_new)^T
            const int d = t >> 1, half = t & 1;
            unsigned o[8];
            #pragma unroll
            for (int k = 0; k < 8; ++k) {
                const int r0 = half * 16 + 2 * k;
                const float lo = bf2f(xl[r0 * 136 + d]) * dw_l[r0];
                const float hi = bf2f(xl[(r0 + 1) * 136 + d]) * dw_l[r0 + 1];
                o[k] = f2bf(lo) | ((unsigned)f2bf(hi) << 16);
            }
            i32x4 v0 = {(int)o[0],(int)o[1],(int)o[2],(int)o[3]};
            i32x4 v1 = {(int)o[4],(int)o[5],(int)o[6],(int)o[7]};
            i32x4* dst = (i32x4*)(xwT_next + (size_t)(b * DD + d) * NN + i0 + half * 16);
            dst[0] = v0; dst[1] = v1;
        }
    }
}

extern "C" void kernel_launch(void* const* d_in, const int* in_sizes, int n_in,
                              void* d_out, int out_size, void* d_ws, size_t ws_size,
                              hipStream_t stream) {
    const float* node   = (const float*)d_in[0];
    const int*   mask   = (const int*)  d_in[1];
    const int*   punct  = (const int*)  d_in[2];
    const float* w_nw   = (const float*)d_in[3];
    const float* b_nw   = (const float*)d_in[4];
    const float* w_self = (const float*)d_in[5];
    const float* b_self = (const float*)d_in[6];
    const float* w_punct= (const float*)d_in[7];

    float* xout = (float*)d_out;
    float* aw   = xout + (size_t)BB * NN * DD;

    char* w = (char*)d_ws;
    unsigned*       pk    = (unsigned*)w;                                 // 4 MB
    float*          scl   = (float*)(w + (4u<<20));                       // 64 KB
    unsigned short* wc    = (unsigned short*)(w + (4u<<20) + (64u<<10));  // 64 KB
    float*          awdum = (float*)(w + (4u<<20) + (128u<<10));          // 64 KB
    unsigned short* ab0   = (unsigned short*)(w + (5u<<20));              // 8 MB
    unsigned short* ab1   = (unsigned short*)(w + (13u<<20));             // 8 MB
    unsigned short* xwT0  = (unsigned short*)(w + (21u<<20));             // 4 MB
    unsigned short* xwT1  = (unsigned short*)(w + (25u<<20));             // 4 MB

    kernP<<<dim3(8193), dim3(256), 0, stream>>>(punct, mask, w_self, w_punct, pk, scl, wc);
    kernD<<<dim3(1024), dim3(256), 0, stream>>>(node, w_nw, b_nw, aw, ab0, xwT0);
    // step 0 (x_out not needed yet: want_x=0; produce next-step tensors)
    kernC2<<<dim3(512), dim3(512), 0, stream>>>(pk, scl, xwT0, ab0);
    kernF<<<dim3(512), dim3(256), 0, stream>>>(ab0, wc, b_self, w_nw, b_nw,
                                               xout, aw + NN, ab1, xwT1, 0, 1);
    // step 1 (final: want_x=1; no next tensors; dw2 -> dummy)
    kernC2<<<dim3(512), dim3(512), 0, stream>>>(pk, scl, xwT1, ab1);
    kernF<<<dim3(512), dim3(256), 0, stream>>>(ab1, wc, b_self, w_nw, b_nw,
                                               xout, awdum, ab0, xwT0, 1, 0);
}

// Round 8
// 312.163 us; speedup vs baseline: 1.2115x; 1.2115x over previous
//
#include <hip/hip_runtime.h>
#include <hip/hip_bf16.h>

#define BB 8
#define NN 2048
#define DD 128

typedef __attribute__((ext_vector_type(8))) __bf16 bf16x8;
typedef __attribute__((ext_vector_type(4))) float f32x4;
typedef __attribute__((ext_vector_type(4))) int   i32x4;
typedef __attribute__((ext_vector_type(2))) int   i32x2;

static __device__ __forceinline__ unsigned short f2bf(float f) {
    union { float f; unsigned u; } v; v.f = f;
    unsigned r = (v.u + 0x7FFFu + ((v.u >> 16) & 1u)) >> 16;
    return (unsigned short)r;
}
static __device__ __forceinline__ float bf2f(unsigned short b) {
    union { unsigned u; float f; } v; v.u = ((unsigned)b) << 16;
    return v.f;
}

// ---------------------------------------------------------------------------
// kernP (unchanged, R7-proven): pack Ptilde bits (diag cleared) + scale.
// Block 8192 casts Wc[e][k] (k<128: w_self, else w_punct) to bf16.
// ---------------------------------------------------------------------------
__global__ __launch_bounds__(256) void kernP(
    const int* __restrict__ punct, const int* __restrict__ mask,
    const float* __restrict__ w_self, const float* __restrict__ w_punct,
    unsigned* __restrict__ pk, float* __restrict__ scale_g,
    unsigned short* __restrict__ wc)
{
    const int t = threadIdx.x;
    if (blockIdx.x == 8192) {
        for (int idx = t; idx < 128 * 256; idx += 256) {
            const int e = idx >> 8, k = idx & 255;
            const float v = (k < 128) ? w_self[e * 128 + k]
                                      : w_punct[e * 128 + (k - 128)];
            wc[idx] = f2bf(v);
        }
        return;
    }
    __shared__ unsigned char nib[2][512];

    const int rl = t >> 7;
    const int u  = t & 127;
    const int row_g = blockIdx.x * 2 + rl;
    const int b = row_g >> 11;

    const int* prow = punct + (size_t)row_g * NN;
    const int* mrow = mask + (size_t)b * NN;

    #pragma unroll
    for (int p = 0; p < 4; ++p) {
        const int col = p * 512 + u * 4;
        i32x4 pv = *(const i32x4*)(prow + col);
        i32x4 mv = *(const i32x4*)(mrow + col);
        unsigned n = (unsigned)((pv.x & mv.x & 1) | ((pv.y & mv.y & 1) << 1)
                              | ((pv.z & mv.z & 1) << 2) | ((pv.w & mv.w & 1) << 3));
        nib[rl][p * 128 + u] = (unsigned char)n;
    }
    __syncthreads();

    if (t < 128) {
        const int r2 = t >> 6, w = t & 63;
        const int rg2 = blockIdx.x * 2 + r2;
        const int i2 = rg2 & (NN - 1);
        const unsigned* np = (const unsigned*)&nib[r2][w * 8];
        unsigned a = np[0], c = np[1];
        a = (a | (a >> 4)) & 0x00FF00FFu;  a = (a | (a >> 8)) & 0x0000FFFFu;
        c = (c | (c >> 4)) & 0x00FF00FFu;  c = (c | (c >> 8)) & 0x0000FFFFu;
        unsigned pw = a | (c << 16);
        if ((i2 >> 5) == w) pw &= ~(1u << (i2 & 31));
        pk[(size_t)rg2 * 64 + w] = pw;

        int cnt = __popc(pw);
        #pragma unroll
        for (int o = 32; o > 0; o >>= 1) cnt += __shfl_xor(cnt, o, 64);
        if (w == 0) {
            const int mi = mask[(size_t)(rg2 >> 11) * NN + i2];
            scale_g[rg2] = mi ? 1.f / (float)(cnt < 1 ? 1 : cnt) : 0.f;
        }
    }
}

// ---------------------------------------------------------------------------
// kernX: cast node f32 -> ab[:, :128] bf16. 16 rows/block, fully coalesced.
// ---------------------------------------------------------------------------
__global__ __launch_bounds__(256) void kernX(
    const float* __restrict__ x, unsigned short* __restrict__ ab)
{
    const int t = threadIdx.x;
    const int row = blockIdx.x * 16 + (t >> 4);
    const int c0 = (t & 15) * 8;
    const float* xs = x + (size_t)row * DD + c0;
    f32x4 a0 = *(const f32x4*)xs;
    f32x4 a1 = *(const f32x4*)(xs + 4);
    unsigned w0 = f2bf(a0.x) | ((unsigned)f2bf(a0.y) << 16);
    unsigned w1 = f2bf(a0.z) | ((unsigned)f2bf(a0.w) << 16);
    unsigned w2 = f2bf(a1.x) | ((unsigned)f2bf(a1.y) << 16);
    unsigned w3 = f2bf(a1.z) | ((unsigned)f2bf(a1.w) << 16);
    i32x4 pw = {(int)w0,(int)w1,(int)w2,(int)w3};
    *(i32x4*)(ab + (size_t)row * 256 + c0) = pw;
}

// ---------------------------------------------------------------------------
// kernT: dedicated transpose + dw. Reads xb = ab[:, :128] (bf16 row-major),
// computes dw = sigmoid(x.w_nw + b_nw) -> aw (+step offset via ptr),
// writes xwT[b][d][n] = dw[n]*x[n][d]. LDS stride 132 u16 (66 words, bank
// step 2 -> ~free 2-way on both the staging and transpose-read phases).
// 64 rows/block, 256 blocks.
// ---------------------------------------------------------------------------
__global__ __launch_bounds__(256) void kernT(
    const unsigned short* __restrict__ xb,   // [B*N][256], cols 0..127 valid
    const float* __restrict__ w_nw, const float* __restrict__ b_nw,
    float* __restrict__ aw_out,              // aw + step*NN (kernel adds b*2N)
    unsigned short* __restrict__ xwT)        // [B][D][N]
{
    __shared__ unsigned short xl[64 * 132];
    __shared__ float wnw_l[DD];
    __shared__ float red4[64 * 4];
    __shared__ float dw_l[64];

    const int t  = threadIdx.x;
    const int n0 = blockIdx.x * 64;
    const int b  = n0 >> 11;
    const int nb = n0 & (NN - 1);

    if (t < DD) wnw_l[t] = w_nw[t];

    {   // stage 64x128 bf16 tile, coalesced 16 B loads, b64 LDS writes
        const int cb = t & 15;
        #pragma unroll
        for (int j = 0; j < 4; ++j) {
            const int row = j * 16 + (t >> 4);
            i32x4 v = *(const i32x4*)(xb + (size_t)(n0 + row) * 256 + cb * 8);
            i32x2 lo = {v.x, v.y}, hi = {v.z, v.w};
            *(i32x2*)&xl[row * 132 + cb * 8]     = lo;
            *(i32x2*)&xl[row * 132 + cb * 8 + 4] = hi;
        }
    }
    __syncthreads();

    {   // dw: thread (row=t>>2, q=t&3) dots 32 cols via b64 LDS reads
        const int row = t >> 2, q = t & 3;
        float dp = 0.f;
        #pragma unroll
        for (int k = 0; k < 8; ++k) {
            i32x2 v = *(const i32x2*)&xl[row * 132 + q * 32 + k * 4];
            const float* wv = &wnw_l[q * 32 + k * 4];
            dp += bf2f((unsigned short)(v.x & 0xFFFF)) * wv[0]
                + bf2f((unsigned short)((unsigned)v.x >> 16)) * wv[1]
                + bf2f((unsigned short)(v.y & 0xFFFF)) * wv[2]
                + bf2f((unsigned short)((unsigned)v.y >> 16)) * wv[3];
        }
        red4[row * 4 + q] = dp;
    }
    __syncthreads();
    if (t < 64) {
        float s = red4[4*t] + red4[4*t+1] + red4[4*t+2] + red4[4*t+3] + b_nw[0];
        float dv = 1.f / (1.f + __expf(-s));
        dw_l[t] = dv;
        aw_out[(size_t)b * 2 * NN + nb + t] = dv;
    }
    __syncthreads();

    {   // transpose write: thread (d=t>>1, half=t&1) emits 32 u16 (64 B) of row d
        const int d = t >> 1, half = t & 1;
        unsigned o[16];
        #pragma unroll
        for (int k = 0; k < 16; ++k) {
            const int r0 = half * 32 + 2 * k;
            const float lo = bf2f(xl[r0 * 132 + d]) * dw_l[r0];
            const float hi = bf2f(xl[(r0 + 1) * 132 + d]) * dw_l[r0 + 1];
            o[k] = f2bf(lo) | ((unsigned)f2bf(hi) << 16);
        }
        i32x4* dst = (i32x4*)(xwT + (size_t)(b * DD + d) * NN + nb + half * 32);
        i32x4 v0 = {(int)o[0],(int)o[1],(int)o[2],(int)o[3]};
        i32x4 v1 = {(int)o[4],(int)o[5],(int)o[6],(int)o[7]};
        i32x4 v2 = {(int)o[8],(int)o[9],(int)o[10],(int)o[11]};
        i32x4 v3 = {(int)o[12],(int)o[13],(int)o[14],(int)o[15]};
        dst[0]=v0; dst[1]=v1; dst[2]=v2; dst[3]=v3;
    }
}

// ---------------------------------------------------------------------------
// kernC3: phase 1 (R3-proven shape): Z = bitP @ xwT, 64 rows/block, 4 waves,
// zero-barrier K-loop. Epilogue: ONLY coalesced u16 stores of
// Zs = scale*Z into ab[:, 128:256].
// ---------------------------------------------------------------------------
__global__ __launch_bounds__(256) void kernC3(
    const unsigned* __restrict__ pk, const float* __restrict__ scale_g,
    const unsigned short* __restrict__ xwT,   // [B][D][N]
    unsigned short* __restrict__ ab)          // [B*N][256], cols 128..255
{
    __shared__ unsigned pPk[64 * 68];
    __shared__ float scale_l[64];

    const int t  = threadIdx.x;
    const int b  = blockIdx.x >> 5;
    const int i0 = (blockIdx.x & 31) * 64;
    const size_t rg0 = (size_t)b * NN + i0;

    #pragma unroll
    for (int r = 0; r < 4; ++r) {
        const int u = r * 256 + t;
        const int row = u >> 4;
        const int wq  = (u & 15) * 4;
        i32x4 v = *(const i32x4*)(pk + (rg0 + row) * 64 + wq);
        *(i32x4*)&pPk[row * 68 + wq] = v;
    }
    if (t < 64) scale_l[t] = scale_g[rg0 + t];
    __syncthreads();

    const int wn = t >> 6, lane = t & 63;
    const int quad = lane >> 4, l16 = lane & 15;
    const unsigned short* xwTb = xwT + (size_t)b * DD * NN;

    f32x4 acc[4][2] = {};
    #pragma unroll 4
    for (int kk = 0; kk < 64; ++kk) {
        bf16x8 bfr[2];
        #pragma unroll
        for (int nt = 0; nt < 2; ++nt) {
            const int d = wn*32 + nt*16 + l16;
            bfr[nt] = *(const bf16x8*)(xwTb + (size_t)d * NN + kk*32 + quad*8);
        }
        bf16x8 af[4];
        #pragma unroll
        for (int mt = 0; mt < 4; ++mt) {
            const unsigned w = pPk[(mt*16 + l16) * 68 + kk];
            const unsigned by = (w >> (quad * 8)) & 0xFFu;
            i32x4 ex;
            ex.x = ((by &   1u) ? 0x3F80 : 0) | ((by &   2u) ? 0x3F800000 : 0);
            ex.y = ((by &   4u) ? 0x3F80 : 0) | ((by &   8u) ? 0x3F800000 : 0);
            ex.z = ((by &  16u) ? 0x3F80 : 0) | ((by &  32u) ? 0x3F800000 : 0);
            ex.w = ((by &  64u) ? 0x3F80 : 0) | ((by & 128u) ? 0x3F800000 : 0);
            union { i32x4 i; bf16x8 h; } cv; cv.i = ex;
            af[mt] = cv.h;
        }
        #pragma unroll
        for (int mt = 0; mt < 4; ++mt)
            #pragma unroll
            for (int nt = 0; nt < 2; ++nt)
                acc[mt][nt] = __builtin_amdgcn_mfma_f32_16x16x32_bf16(af[mt], bfr[nt], acc[mt][nt], 0, 0, 0);
    }

    #pragma unroll
    for (int mt = 0; mt < 4; ++mt) {
        #pragma unroll
        for (int nt = 0; nt < 2; ++nt) {
            const int d = wn*32 + nt*16 + l16;
            #pragma unroll
            for (int r = 0; r < 4; ++r) {
                const int row = mt*16 + quad*4 + r;
                ab[(rg0 + row) * 256 + 128 + d] = f2bf(scale_l[row] * acc[mt][nt][r]);
            }
        }
    }
}

// ---------------------------------------------------------------------------
// kernG: out = relu([xbf|Zs] @ Wc^T + b_self), K=256. 64 rows/block, 4 waves,
// NO LDS. final: f32 -> x_out (coalesced 16-lane runs); else bf16 ->
// ab_next[:, :128] (coalesced 32-B runs).
// ---------------------------------------------------------------------------
__global__ __launch_bounds__(256) void kernG(
    const unsigned short* __restrict__ ab,    // [B*N][256]
    const unsigned short* __restrict__ wc,    // [128][256]
    const float* __restrict__ b_self,
    float* __restrict__ x_out, unsigned short* __restrict__ ab_next,
    int final_step)
{
    const int t  = threadIdx.x;
    const size_t rg0 = (size_t)blockIdx.x * 64;

    const int wn = t >> 6, lane = t & 63;
    const int quad = lane >> 4, l16 = lane & 15;

    f32x4 acc[4][2] = {};
    #pragma unroll
    for (int kq = 0; kq < 8; ++kq) {
        bf16x8 b2[2];
        #pragma unroll
        for (int nt = 0; nt < 2; ++nt) {
            const int e = wn*32 + nt*16 + l16;
            b2[nt] = *(const bf16x8*)(wc + (size_t)e * 256 + kq*32 + quad*8);
        }
        bf16x8 a2[4];
        #pragma unroll
        for (int mt = 0; mt < 4; ++mt)
            a2[mt] = *(const bf16x8*)(ab + (rg0 + mt*16 + l16) * 256 + kq*32 + quad*8);
        #pragma unroll
        for (int mt = 0; mt < 4; ++mt)
            #pragma unroll
            for (int nt = 0; nt < 2; ++nt)
                acc[mt][nt] = __builtin_amdgcn_mfma_f32_16x16x32_bf16(a2[mt], b2[nt], acc[mt][nt], 0, 0, 0);
    }

    float bias[2];
    #pragma unroll
    for (int nt = 0; nt < 2; ++nt) bias[nt] = b_self[wn*32 + nt*16 + l16];

    #pragma unroll
    for (int mt = 0; mt < 4; ++mt) {
        #pragma unroll
        for (int nt = 0; nt < 2; ++nt) {
            const int e = wn*32 + nt*16 + l16;
            #pragma unroll
            for (int r = 0; r < 4; ++r) {
                const int row = mt*16 + quad*4 + r;
                const float v = fmaxf(acc[mt][nt][r] + bias[nt], 0.f);
                if (final_step) x_out[(rg0 + row) * DD + e] = v;
                else            ab_next[(rg0 + row) * 256 + e] = f2bf(v);
            }
        }
    }
}

extern "C" void kernel_launch(void* const* d_in, const int* in_sizes, int n_in,
                              void* d_out, int out_size, void* d_ws, size_t ws_size,
                              hipStream_t stream) {
    const float* node   = (const float*)d_in[0];
    const int*   mask   = (const int*)  d_in[1];
    const int*   punct  = (const int*)  d_in[2];
    const float* w_nw   = (const float*)d_in[3];
    const float* b_nw   = (const float*)d_in[4];
    const float* w_self = (const float*)d_in[5];
    const float* b_self = (const float*)d_in[6];
    const float* w_punct= (const float*)d_in[7];

    float* xout = (float*)d_out;
    float* aw   = xout + (size_t)BB * NN * DD;

    char* w = (char*)d_ws;
    unsigned*       pk   = (unsigned*)w;                                 // 4 MB
    float*          scl  = (float*)(w + (4u<<20));                       // 64 KB
    unsigned short* wc   = (unsigned short*)(w + (4u<<20) + (64u<<10));  // 64 KB
    unsigned short* ab0  = (unsigned short*)(w + (5u<<20));              // 8 MB
    unsigned short* ab1  = (unsigned short*)(w + (13u<<20));             // 8 MB
    unsigned short* xwT0 = (unsigned short*)(w + (21u<<20));             // 4 MB
    unsigned short* xwT1 = (unsigned short*)(w + (25u<<20));             // 4 MB

    dim3 blk(256);
    kernP <<<dim3(8193), blk, 0, stream>>>(punct, mask, w_self, w_punct, pk, scl, wc);
    kernX <<<dim3(1024), blk, 0, stream>>>(node, ab0);
    kernT <<<dim3(256),  blk, 0, stream>>>(ab0, w_nw, b_nw, aw, xwT0);        // dw0 -> aw[:,0,:]
    // step 0
    kernC3<<<dim3(256),  blk, 0, stream>>>(pk, scl, xwT0, ab0);
    kernG <<<dim3(256),  blk, 0, stream>>>(ab0, wc, b_self, xout, ab1, 0);
    kernT <<<dim3(256),  blk, 0, stream>>>(ab1, w_nw, b_nw, aw + NN, xwT1);   // dw1 -> aw[:,1,:]
    // step 1
    kernC3<<<dim3(256),  blk, 0, stream>>>(pk, scl, xwT1, ab1);
    kernG <<<dim3(256),  blk, 0, stream>>>(ab1, wc, b_self, xout, ab0, 1);
}